// Round 1
// baseline (489.209 us; speedup 1.0000x reference)
//
#include <hip/hip_runtime.h>
#include <hip/hip_bf16.h>

#define N_NODES 50000
#define N_EDGES 1600000
#define D 512

typedef __attribute__((ext_vector_type(8))) short short8;
typedef __attribute__((ext_vector_type(4))) float f32x4;
typedef __attribute__((ext_vector_type(4))) unsigned short u16x4;

// --- W transpose + fp32->bf16 cast: Wt[n][k] = bf16(W[k][n]) ---
__global__ __launch_bounds__(256) void wt_kernel(const float* __restrict__ W,
                                                 __hip_bfloat16* __restrict__ Wt) {
    int idx = blockIdx.x * 256 + threadIdx.x;   // over 512*512
    int k = idx >> 9;
    int n = idx & 511;
    Wt[n * D + k] = __float2bfloat16(W[k * D + n]);
}

// --- CSR row_start from sorted adj_rows via binary search (lower_bound) ---
__global__ __launch_bounds__(256) void rowptr_kernel(const int* __restrict__ rows,
                                                     int* __restrict__ row_start) {
    int r = blockIdx.x * 256 + threadIdx.x;
    if (r > N_NODES) return;
    int lo = 0, hi = N_EDGES;
    while (lo < hi) {
        int mid = (lo + hi) >> 1;
        if (rows[mid] < r) lo = mid + 1; else hi = mid;
    }
    row_start[r] = lo;   // row_start[N_NODES] == N_EDGES automatically
}

// --- support = bf16( X @ W ), MFMA 16x16x32 bf16, 128x128 tile, BK=32 ---
__global__ __launch_bounds__(256) void gemm_kernel(const float* __restrict__ X,
                                                   const __hip_bfloat16* __restrict__ Wt,
                                                   __hip_bfloat16* __restrict__ support) {
    __shared__ __hip_bfloat16 As[128][40];   // +8 pad: 80B row stride, no 4-way+ conflicts
    __shared__ __hip_bfloat16 Bs[128][40];

    const int t = threadIdx.x;
    const int lane = t & 63;
    const int wave = t >> 6;
    const int wm = (wave & 1) * 64;
    const int wn = (wave >> 1) * 64;
    const int m0 = blockIdx.x * 128;
    const int n0 = blockIdx.y * 128;
    const int l15 = lane & 15;
    const int quad = lane >> 4;

    f32x4 acc[4][4];
#pragma unroll
    for (int i = 0; i < 4; ++i)
#pragma unroll
        for (int j = 0; j < 4; ++j) acc[i][j] = (f32x4)(0.0f);

    const int sr = t >> 3;        // staging row within 32-row group
    const int sc = (t & 7) * 4;   // staging col (k), 4 elements

    for (int kt = 0; kt < D / 32; ++kt) {
        const int k0 = kt * 32;
#pragma unroll
        for (int i = 0; i < 4; ++i) {
            int r = sr + i * 32;
            int gr = m0 + r;
            f32x4 v = (f32x4)(0.0f);
            if (gr < N_NODES) v = *(const f32x4*)(X + (size_t)gr * D + k0 + sc);
            u16x4 u;
            u[0] = __bfloat16_as_ushort(__float2bfloat16(v[0]));
            u[1] = __bfloat16_as_ushort(__float2bfloat16(v[1]));
            u[2] = __bfloat16_as_ushort(__float2bfloat16(v[2]));
            u[3] = __bfloat16_as_ushort(__float2bfloat16(v[3]));
            *(u16x4*)&As[r][sc] = u;
            *(u16x4*)&Bs[r][sc] =
                *(const u16x4*)((const unsigned short*)Wt + (size_t)(n0 + r) * D + k0 + sc);
        }
        __syncthreads();

        short8 af[4], bf[4];
#pragma unroll
        for (int i = 0; i < 4; ++i) af[i] = *(const short8*)&As[wm + i * 16 + l15][quad * 8];
#pragma unroll
        for (int j = 0; j < 4; ++j) bf[j] = *(const short8*)&Bs[wn + j * 16 + l15][quad * 8];
#pragma unroll
        for (int i = 0; i < 4; ++i)
#pragma unroll
            for (int j = 0; j < 4; ++j)
                acc[i][j] = __builtin_amdgcn_mfma_f32_16x16x32_bf16(af[i], bf[j], acc[i][j], 0, 0, 0);
        __syncthreads();
    }

    // epilogue: C/D layout col=lane&15, row=quad*4+reg  [measured m89/m91]
#pragma unroll
    for (int i = 0; i < 4; ++i) {
        int grb = m0 + wm + i * 16 + quad * 4;
#pragma unroll
        for (int j = 0; j < 4; ++j) {
            int gc = n0 + wn + j * 16 + l15;
#pragma unroll
            for (int r = 0; r < 4; ++r) {
                int gr = grb + r;
                if (gr < N_NODES)
                    support[(size_t)gr * D + gc] = __float2bfloat16(acc[i][j][r]);
            }
        }
    }
}

// --- out[r,:] = sum_{e in row r} vals[e] * support[cols[e],:]  (one block/row) ---
__global__ __launch_bounds__(256) void spmm_kernel(const __hip_bfloat16* __restrict__ support,
                                                   const int* __restrict__ cols,
                                                   const float* __restrict__ vals,
                                                   const int* __restrict__ row_start,
                                                   float* __restrict__ out) {
    const int r = blockIdx.x;
    const int t = threadIdx.x;   // 256 threads x 2 cols each = 512
    const int s = row_start[r];
    const int e = row_start[r + 1];
    float ax = 0.f, ay = 0.f;
    int i = s;
    for (; i + 4 <= e; i += 4) {   // 4-wide unroll: 4 outstanding gathers
        int c0 = cols[i], c1 = cols[i + 1], c2 = cols[i + 2], c3 = cols[i + 3];
        float v0 = vals[i], v1 = vals[i + 1], v2 = vals[i + 2], v3 = vals[i + 3];
        __hip_bfloat162 h0 = *(const __hip_bfloat162*)(support + (size_t)c0 * D + 2 * t);
        __hip_bfloat162 h1 = *(const __hip_bfloat162*)(support + (size_t)c1 * D + 2 * t);
        __hip_bfloat162 h2 = *(const __hip_bfloat162*)(support + (size_t)c2 * D + 2 * t);
        __hip_bfloat162 h3 = *(const __hip_bfloat162*)(support + (size_t)c3 * D + 2 * t);
        ax += v0 * __bfloat162float(h0.x) + v1 * __bfloat162float(h1.x)
            + v2 * __bfloat162float(h2.x) + v3 * __bfloat162float(h3.x);
        ay += v0 * __bfloat162float(h0.y) + v1 * __bfloat162float(h1.y)
            + v2 * __bfloat162float(h2.y) + v3 * __bfloat162float(h3.y);
    }
    for (; i < e; ++i) {
        int c = cols[i];
        float v = vals[i];
        __hip_bfloat162 h = *(const __hip_bfloat162*)(support + (size_t)c * D + 2 * t);
        ax += v * __bfloat162float(h.x);
        ay += v * __bfloat162float(h.y);
    }
    float2 o; o.x = ax; o.y = ay;
    *(float2*)(out + (size_t)r * D + 2 * t) = o;   // full coverage incl. degree-0 rows
}

extern "C" void kernel_launch(void* const* d_in, const int* in_sizes, int n_in,
                              void* d_out, int out_size, void* d_ws, size_t ws_size,
                              hipStream_t stream) {
    (void)in_sizes; (void)n_in; (void)out_size; (void)ws_size;
    const float* X   = (const float*)d_in[0];
    const float* W   = (const float*)d_in[1];
    const int* rows  = (const int*)d_in[2];
    const int* cols  = (const int*)d_in[3];
    const float* vals = (const float*)d_in[4];
    float* out = (float*)d_out;

    // workspace layout
    __hip_bfloat16* support = (__hip_bfloat16*)d_ws;                 // 51,200,000 B
    __hip_bfloat16* Wt      = support + (size_t)N_NODES * D;         //    524,288 B
    int* row_start          = (int*)(Wt + (size_t)D * D);            //    200,004 B

    wt_kernel<<<(D * D) / 256, 256, 0, stream>>>(W, Wt);
    rowptr_kernel<<<(N_NODES + 256) / 256, 256, 0, stream>>>(rows, row_start);

    dim3 gg((N_NODES + 127) / 128, D / 128);
    gemm_kernel<<<gg, 256, 0, stream>>>(X, Wt, support);

    spmm_kernel<<<N_NODES, 256, 0, stream>>>(support, cols, vals, row_start, out);
}

// Round 2
// 472.822 us; speedup vs baseline: 1.0347x; 1.0347x over previous
//
#include <hip/hip_runtime.h>
#include <hip/hip_bf16.h>

#define N_NODES 50000
#define N_EDGES 1600000
#define D 512

typedef __attribute__((ext_vector_type(8))) short short8;
typedef __attribute__((ext_vector_type(4))) float f32x4;
typedef __attribute__((ext_vector_type(4))) unsigned short u16x4;
typedef __attribute__((ext_vector_type(8))) unsigned short u16x8;

__device__ __forceinline__ void async_copy16(const void* g, void* l) {
    __builtin_amdgcn_global_load_lds(
        (const __attribute__((address_space(1))) unsigned int*)g,
        (__attribute__((address_space(3))) unsigned int*)l, 16, 0, 0);
}

// --- X fp32 -> bf16 prepass (Xb lives in d_out's first 51.2 MB, overwritten later) ---
__global__ __launch_bounds__(256) void cvt_kernel(const float* __restrict__ X,
                                                  unsigned short* __restrict__ Xb) {
    size_t idx = (size_t)(blockIdx.x * 256 + threadIdx.x) * 8;   // 12500 blocks covers 25.6M exactly
    f32x4 v0 = *(const f32x4*)(X + idx);
    f32x4 v1 = *(const f32x4*)(X + idx + 4);
    u16x8 u;
#pragma unroll
    for (int k = 0; k < 4; ++k) {
        u[k]     = __bfloat16_as_ushort(__float2bfloat16(v0[k]));
        u[k + 4] = __bfloat16_as_ushort(__float2bfloat16(v1[k]));
    }
    *(u16x8*)(Xb + idx) = u;
}

// --- W transpose + cast: Wt[n][k] = bf16(W[k][n]) ---
__global__ __launch_bounds__(256) void wt_kernel(const float* __restrict__ W,
                                                 unsigned short* __restrict__ Wt) {
    int idx = blockIdx.x * 256 + threadIdx.x;
    int k = idx >> 9;
    int n = idx & 511;
    Wt[n * D + k] = __bfloat16_as_ushort(__float2bfloat16(W[k * D + n]));
}

// --- CSR row_start from sorted adj_rows ---
__global__ __launch_bounds__(256) void rowptr_kernel(const int* __restrict__ rows,
                                                     int* __restrict__ row_start) {
    int r = blockIdx.x * 256 + threadIdx.x;
    if (r > N_NODES) return;
    int lo = 0, hi = N_EDGES;
    while (lo < hi) {
        int mid = (lo + hi) >> 1;
        if (rows[mid] < r) lo = mid + 1; else hi = mid;
    }
    row_start[r] = lo;
}

// --- support = bf16(Xb @ Wt^T), m97-style: global_load_lds(16B) + ds_read_b128 ---
__global__ __launch_bounds__(256) void gemm_kernel(const unsigned short* __restrict__ Xb,
                                                   const unsigned short* __restrict__ Wt,
                                                   __hip_bfloat16* __restrict__ support) {
    __shared__ unsigned short As[128 * 32];   // [row][k], unpadded: global_load_lds needs lane-order
    __shared__ unsigned short Bs[128 * 32];

    const int t = threadIdx.x;
    const int lane = t & 63;
    const int wave = t >> 6;
    const int wm = (wave & 1) * 64;
    const int wn = (wave >> 1) * 64;
    const int m0 = blockIdx.x * 128;
    const int n0 = blockIdx.y * 128;
    const int l15 = lane & 15;
    const int quad = lane >> 4;

    f32x4 acc[4][4];
#pragma unroll
    for (int i = 0; i < 4; ++i)
#pragma unroll
        for (int j = 0; j < 4; ++j) acc[i][j] = (f32x4)(0.0f);

    // staging map: thread t -> row (t>>2) within 64-row group, k-slice (t&3)*8
    // LDS offset = row*32 + (t&3)*8 = t*8 elements -> wave-contiguous (base + lane*16B) ✓
    const int srow = t >> 2;
    const int skb = (t & 3) * 8;
    int gra = m0 + srow;        if (gra > N_NODES - 1) gra = N_NODES - 1;  // clamp: dup rows, never stored
    int grb = m0 + 64 + srow;   if (grb > N_NODES - 1) grb = N_NODES - 1;
    const size_t aoff0 = (size_t)gra * D + skb;
    const size_t aoff1 = (size_t)grb * D + skb;
    const size_t boff0 = (size_t)(n0 + srow) * D + skb;
    const size_t boff1 = (size_t)(n0 + 64 + srow) * D + skb;
    unsigned short* lA = As + t * 8;
    unsigned short* lB = Bs + t * 8;

    for (int kt = 0; kt < D / 32; ++kt) {
        const int k0 = kt * 32;
        async_copy16(Xb + aoff0 + k0, lA);
        async_copy16(Xb + aoff1 + k0, lA + 2048);
        async_copy16(Wt + boff0 + k0, lB);
        async_copy16(Wt + boff1 + k0, lB + 2048);
        __syncthreads();   // drains vmcnt (incl. global_load_lds) before use

        short8 af[4], bf[4];
#pragma unroll
        for (int i = 0; i < 4; ++i) af[i] = *(const short8*)(As + (wm + i * 16 + l15) * 32 + quad * 8);
#pragma unroll
        for (int j = 0; j < 4; ++j) bf[j] = *(const short8*)(Bs + (wn + j * 16 + l15) * 32 + quad * 8);
#pragma unroll
        for (int i = 0; i < 4; ++i)
#pragma unroll
            for (int j = 0; j < 4; ++j)
                acc[i][j] = __builtin_amdgcn_mfma_f32_16x16x32_bf16(af[i], bf[j], acc[i][j], 0, 0, 0);
        __syncthreads();
    }

    // C/D layout: col=lane&15, row=quad*4+reg [m89/m91]
#pragma unroll
    for (int i = 0; i < 4; ++i) {
        int grow = m0 + wm + i * 16 + quad * 4;
#pragma unroll
        for (int j = 0; j < 4; ++j) {
            int gc = n0 + wn + j * 16 + l15;
#pragma unroll
            for (int rr = 0; rr < 4; ++rr) {
                int gr = grow + rr;
                if (gr < N_NODES)
                    support[(size_t)gr * D + gc] = __float2bfloat16(acc[i][j][rr]);
            }
        }
    }
}

// --- SpMM: one wave per row, 16B/lane gathers, 4-edge unroll (64B/lane in flight) ---
__global__ __launch_bounds__(256) void spmm_kernel(const unsigned short* __restrict__ support,
                                                   const int* __restrict__ cols,
                                                   const float* __restrict__ vals,
                                                   const int* __restrict__ row_start,
                                                   float* __restrict__ out) {
    const int wave = threadIdx.x >> 6;
    const int lane = threadIdx.x & 63;
    const int r = blockIdx.x * 4 + wave;
    if (r >= N_NODES) return;
    const int s = row_start[r];
    const int e = row_start[r + 1];
    const int co = lane * 8;                  // 8 cols per lane, 64 lanes = 512 cols

    float acc[8];
#pragma unroll
    for (int k = 0; k < 8; ++k) acc[k] = 0.f;

    int i = s;
    for (; i + 4 <= e; i += 4) {
        int c0 = cols[i], c1 = cols[i + 1], c2 = cols[i + 2], c3 = cols[i + 3];
        float v0 = vals[i], v1 = vals[i + 1], v2 = vals[i + 2], v3 = vals[i + 3];
        u16x8 h0 = *(const u16x8*)(support + (size_t)c0 * D + co);
        u16x8 h1 = *(const u16x8*)(support + (size_t)c1 * D + co);
        u16x8 h2 = *(const u16x8*)(support + (size_t)c2 * D + co);
        u16x8 h3 = *(const u16x8*)(support + (size_t)c3 * D + co);
#pragma unroll
        for (int k = 0; k < 8; ++k) {
            acc[k] += v0 * __uint_as_float((unsigned)h0[k] << 16)
                    + v1 * __uint_as_float((unsigned)h1[k] << 16)
                    + v2 * __uint_as_float((unsigned)h2[k] << 16)
                    + v3 * __uint_as_float((unsigned)h3[k] << 16);
        }
    }
    for (; i < e; ++i) {
        int c = cols[i];
        float v = vals[i];
        u16x8 h = *(const u16x8*)(support + (size_t)c * D + co);
#pragma unroll
        for (int k = 0; k < 8; ++k) acc[k] += v * __uint_as_float((unsigned)h[k] << 16);
    }

    f32x4 o0, o1;
#pragma unroll
    for (int k = 0; k < 4; ++k) { o0[k] = acc[k]; o1[k] = acc[k + 4]; }
    *(f32x4*)(out + (size_t)r * D + co) = o0;
    *(f32x4*)(out + (size_t)r * D + co + 4) = o1;
}

extern "C" void kernel_launch(void* const* d_in, const int* in_sizes, int n_in,
                              void* d_out, int out_size, void* d_ws, size_t ws_size,
                              hipStream_t stream) {
    (void)in_sizes; (void)n_in; (void)out_size; (void)ws_size;
    const float* X    = (const float*)d_in[0];
    const float* W    = (const float*)d_in[1];
    const int* rows   = (const int*)d_in[2];
    const int* cols   = (const int*)d_in[3];
    const float* vals = (const float*)d_in[4];
    float* out = (float*)d_out;

    // workspace: support bf16 (51.2MB) | Wt bf16 (0.5MB) | row_start (200KB)
    unsigned short* support = (unsigned short*)d_ws;
    unsigned short* Wt      = support + (size_t)N_NODES * D;
    int* row_start          = (int*)(Wt + (size_t)D * D);
    // Xb scratch: first 51.2MB of d_out (102.4MB) — spmm overwrites it at the end
    unsigned short* Xb = (unsigned short*)d_out;

    cvt_kernel<<<12500, 256, 0, stream>>>(X, Xb);
    wt_kernel<<<(D * D) / 256, 256, 0, stream>>>(W, Wt);
    rowptr_kernel<<<(N_NODES + 256) / 256, 256, 0, stream>>>(rows, row_start);

    dim3 gg((N_NODES + 127) / 128, D / 128);
    gemm_kernel<<<gg, 256, 0, stream>>>(Xb, Wt, (__hip_bfloat16*)support);

    spmm_kernel<<<12500, 256, 0, stream>>>(support, cols, vals, row_start, out);
}

// Round 4
// 462.135 us; speedup vs baseline: 1.0586x; 1.0231x over previous
//
#include <hip/hip_runtime.h>
#include <hip/hip_bf16.h>

#define N_NODES 50000
#define N_EDGES 1600000
#define D 512

typedef __attribute__((ext_vector_type(8))) short short8;
typedef __attribute__((ext_vector_type(4))) float f32x4;
typedef __attribute__((ext_vector_type(2))) float f32x2;
typedef __attribute__((ext_vector_type(8))) unsigned short u16x8;

__device__ __forceinline__ void async_copy16(const void* g, void* l) {
    __builtin_amdgcn_global_load_lds(
        (const __attribute__((address_space(1))) unsigned int*)g,
        (__attribute__((address_space(3))) unsigned int*)l, 16, 0, 0);
}

// --- X fp32 -> bf16 prepass (Xb lives in d_out's first 51.2 MB, overwritten later) ---
__global__ __launch_bounds__(256) void cvt_kernel(const float* __restrict__ X,
                                                  unsigned short* __restrict__ Xb) {
    size_t idx = (size_t)(blockIdx.x * 256 + threadIdx.x) * 8;
    f32x4 v0 = *(const f32x4*)(X + idx);
    f32x4 v1 = *(const f32x4*)(X + idx + 4);
    u16x8 u;
#pragma unroll
    for (int k = 0; k < 4; ++k) {
        u[k]     = __bfloat16_as_ushort(__float2bfloat16(v0[k]));
        u[k + 4] = __bfloat16_as_ushort(__float2bfloat16(v1[k]));
    }
    *(u16x8*)(Xb + idx) = u;
}

// --- W transpose + cast: Wt[n][k] = bf16(W[k][n]) ---
__global__ __launch_bounds__(256) void wt_kernel(const float* __restrict__ W,
                                                 unsigned short* __restrict__ Wt) {
    int idx = blockIdx.x * 256 + threadIdx.x;
    int k = idx >> 9;
    int n = idx & 511;
    Wt[n * D + k] = __bfloat16_as_ushort(__float2bfloat16(W[k * D + n]));
}

// --- CSR row_start from sorted adj_rows ---
__global__ __launch_bounds__(256) void rowptr_kernel(const int* __restrict__ rows,
                                                     int* __restrict__ row_start) {
    int r = blockIdx.x * 256 + threadIdx.x;
    if (r > N_NODES) return;
    int lo = 0, hi = N_EDGES;
    while (lo < hi) {
        int mid = (lo + hi) >> 1;
        if (rows[mid] < r) lo = mid + 1; else hi = mid;
    }
    row_start[r] = lo;
}

// --- support = bf16(Xb @ Wt^T) — UNCHANGED from round 2 (attribution control) ---
__global__ __launch_bounds__(256) void gemm_kernel(const unsigned short* __restrict__ Xb,
                                                   const unsigned short* __restrict__ Wt,
                                                   __hip_bfloat16* __restrict__ support) {
    __shared__ unsigned short As[128 * 32];
    __shared__ unsigned short Bs[128 * 32];

    const int t = threadIdx.x;
    const int lane = t & 63;
    const int wave = t >> 6;
    const int wm = (wave & 1) * 64;
    const int wn = (wave >> 1) * 64;
    const int m0 = blockIdx.x * 128;
    const int n0 = blockIdx.y * 128;
    const int l15 = lane & 15;
    const int quad = lane >> 4;

    f32x4 acc[4][4];
#pragma unroll
    for (int i = 0; i < 4; ++i)
#pragma unroll
        for (int j = 0; j < 4; ++j) acc[i][j] = (f32x4)(0.0f);

    const int srow = t >> 2;
    const int skb = (t & 3) * 8;
    int gra = m0 + srow;        if (gra > N_NODES - 1) gra = N_NODES - 1;
    int grb = m0 + 64 + srow;   if (grb > N_NODES - 1) grb = N_NODES - 1;
    const size_t aoff0 = (size_t)gra * D + skb;
    const size_t aoff1 = (size_t)grb * D + skb;
    const size_t boff0 = (size_t)(n0 + srow) * D + skb;
    const size_t boff1 = (size_t)(n0 + 64 + srow) * D + skb;
    unsigned short* lA = As + t * 8;
    unsigned short* lB = Bs + t * 8;

    for (int kt = 0; kt < D / 32; ++kt) {
        const int k0 = kt * 32;
        async_copy16(Xb + aoff0 + k0, lA);
        async_copy16(Xb + aoff1 + k0, lA + 2048);
        async_copy16(Wt + boff0 + k0, lB);
        async_copy16(Wt + boff1 + k0, lB + 2048);
        __syncthreads();

        short8 af[4], bf[4];
#pragma unroll
        for (int i = 0; i < 4; ++i) af[i] = *(const short8*)(As + (wm + i * 16 + l15) * 32 + quad * 8);
#pragma unroll
        for (int j = 0; j < 4; ++j) bf[j] = *(const short8*)(Bs + (wn + j * 16 + l15) * 32 + quad * 8);
#pragma unroll
        for (int i = 0; i < 4; ++i)
#pragma unroll
            for (int j = 0; j < 4; ++j)
                acc[i][j] = __builtin_amdgcn_mfma_f32_16x16x32_bf16(af[i], bf[j], acc[i][j], 0, 0, 0);
        __syncthreads();
    }

#pragma unroll
    for (int i = 0; i < 4; ++i) {
        int grow = m0 + wm + i * 16 + quad * 4;
#pragma unroll
        for (int j = 0; j < 4; ++j) {
            int gc = n0 + wn + j * 16 + l15;
#pragma unroll
            for (int rr = 0; rr < 4; ++rr) {
                int gr = grow + rr;
                if (gr < N_NODES)
                    support[(size_t)gr * D + gc] = __float2bfloat16(acc[i][j][rr]);
            }
        }
    }
}

// --- SpMM: block per row (r1 winner layout), 8-edge unroll, nt-stores ---
__global__ __launch_bounds__(256) void spmm_kernel(const unsigned short* __restrict__ support,
                                                   const int* __restrict__ cols,
                                                   const float* __restrict__ vals,
                                                   const int* __restrict__ row_start,
                                                   float* __restrict__ out) {
    const int r = blockIdx.x;
    const int t = threadIdx.x;           // thread owns cols 2t, 2t+1
    const int s = row_start[r];
    const int e = row_start[r + 1];
    const size_t co = 2 * t;

    float ax = 0.f, ay = 0.f;
    int i = s;
    for (; i + 8 <= e; i += 8) {
        int c[8]; float v[8]; unsigned int h[8];
#pragma unroll
        for (int k = 0; k < 8; ++k) { c[k] = cols[i + k]; v[k] = vals[i + k]; }
#pragma unroll
        for (int k = 0; k < 8; ++k)
            h[k] = *(const unsigned int*)(support + (size_t)c[k] * D + co);
#pragma unroll
        for (int k = 0; k < 8; ++k) {
            ax += v[k] * __uint_as_float(h[k] << 16);          // lo bf16
            ay += v[k] * __uint_as_float(h[k] & 0xffff0000u);  // hi bf16
        }
    }
    for (; i < e; ++i) {
        int c = cols[i];
        float v = vals[i];
        unsigned int h = *(const unsigned int*)(support + (size_t)c * D + co);
        ax += v * __uint_as_float(h << 16);
        ay += v * __uint_as_float(h & 0xffff0000u);
    }
    f32x2 o; o[0] = ax; o[1] = ay;
    // nontemporal: out is streamed once; keep it out of L2 so gathers keep their lines
    __builtin_nontemporal_store(o, (f32x2*)(out + (size_t)r * D + co));
}

extern "C" void kernel_launch(void* const* d_in, const int* in_sizes, int n_in,
                              void* d_out, int out_size, void* d_ws, size_t ws_size,
                              hipStream_t stream) {
    (void)in_sizes; (void)n_in; (void)out_size; (void)ws_size;
    const float* X    = (const float*)d_in[0];
    const float* W    = (const float*)d_in[1];
    const int* rows   = (const int*)d_in[2];
    const int* cols   = (const int*)d_in[3];
    const float* vals = (const float*)d_in[4];
    float* out = (float*)d_out;

    unsigned short* support = (unsigned short*)d_ws;            // 51.2 MB
    unsigned short* Wt      = support + (size_t)N_NODES * D;    // 0.5 MB
    int* row_start          = (int*)(Wt + (size_t)D * D);       // 200 KB
    unsigned short* Xb = (unsigned short*)d_out;                // scratch in d_out, overwritten by spmm

    cvt_kernel<<<12500, 256, 0, stream>>>(X, Xb);
    wt_kernel<<<(D * D) / 256, 256, 0, stream>>>(W, Wt);
    rowptr_kernel<<<(N_NODES + 256) / 256, 256, 0, stream>>>(rows, row_start);

    dim3 gg((N_NODES + 127) / 128, D / 128);
    gemm_kernel<<<gg, 256, 0, stream>>>(Xb, Wt, (__hip_bfloat16*)support);

    spmm_kernel<<<N_NODES, 256, 0, stream>>>(support, cols, vals, row_start, out);
}